// Round 2
// baseline (400.799 us; speedup 1.0000x reference)
//
#include <hip/hip_runtime.h>

// Problem: B=32, S=8192, U=1024, H=1024, axis=1.
// out[b,s,h] = (s - idx[b]) in [0,U) ? quant(updates[b, s-idx[b], h]) : input[b,s,h]
// quant(u) = clip(round_half_even(u / scale[h] + zp[h]), -128, 127), cast to int8.
// Harness dtypes: input -> int32*, indices -> int32*, updates -> float*,
// scales/zp -> float*, out -> INT32* (int8 ref output -> int32 buffer).

#define BB 32
#define SS 8192
#define UU 1024
#define HH 1024

// S*H/4 = 2^21 int4-groups per batch; H/4 = 256 groups per row.
#define ROW_G 256            // H/4
#define BATCH_G (SS * ROW_G) // 2^21

__device__ __forceinline__ int quant1(float u, float sc, float zp) {
    float q = rintf(u / sc + zp);          // round half-to-even, matches jnp.round
    q = fmaxf(q, -128.0f);                 // fmaxf(-inf,-128) = -128  (neginf case)
    q = fminf(q, 127.0f);                  // fminf(+inf, 127) = 127  (posinf case)
    return (int)q;                         // value already integral, in [-128,127]
}

__global__ void scatter_quant_kernel(const int* __restrict__ inp,
                                     const int* __restrict__ idxs,
                                     const float* __restrict__ upd,
                                     const float* __restrict__ scales,
                                     const float* __restrict__ zps,
                                     int* __restrict__ out,
                                     long long n4) {
    long long stride = (long long)gridDim.x * blockDim.x;
    for (long long i = (long long)blockIdx.x * blockDim.x + threadIdx.x;
         i < n4; i += stride) {
        int b  = (int)(i >> 21);               // / BATCH_G
        int r  = (int)(i & (BATCH_G - 1));
        int s  = r >> 8;                       // / ROW_G
        int h4 = r & (ROW_G - 1);

        int idx = idxs[b];                     // 32 values, L1/L2 resident
        unsigned urow = (unsigned)(s - idx);

        int4 o;
        if (urow < (unsigned)UU) {
            const float4 u4 = *reinterpret_cast<const float4*>(
                upd + (((long long)b * UU + urow) * HH + (h4 << 2)));
            const float4 sc = *reinterpret_cast<const float4*>(scales + (h4 << 2));
            const float4 zp = *reinterpret_cast<const float4*>(zps + (h4 << 2));
            o.x = quant1(u4.x, sc.x, zp.x);
            o.y = quant1(u4.y, sc.y, zp.y);
            o.z = quant1(u4.z, sc.z, zp.z);
            o.w = quant1(u4.w, sc.w, zp.w);
        } else {
            o = *reinterpret_cast<const int4*>(inp + (i << 2));
        }
        *reinterpret_cast<int4*>(out + (i << 2)) = o;
    }
}

extern "C" void kernel_launch(void* const* d_in, const int* in_sizes, int n_in,
                              void* d_out, int out_size, void* d_ws, size_t ws_size,
                              hipStream_t stream) {
    const int*   inp    = (const int*)d_in[0];
    const int*   idxs   = (const int*)d_in[1];
    const float* upd    = (const float*)d_in[2];
    const float* scales = (const float*)d_in[3];
    const float* zps    = (const float*)d_in[4];
    int*         out    = (int*)d_out;

    const long long n4 = (long long)BB * SS * (HH / 4);   // 67,108,864
    const int block = 256;
    const int grid  = 2048;   // grid-stride; ~128 iters/thread
    scatter_quant_kernel<<<grid, block, 0, stream>>>(inp, idxs, upd, scales, zps, out, n4);
}